// Round 13
// baseline (39.060 us; speedup 1.0000x reference)
//
#include <hip/hip_runtime.h>

// Problem constants
#define BATCH 512
#define INFEAT 4096
#define LOUT 1023   // code_length - 1
#define NCLS 1000
#define NPAD 1024
#define SPLITK 8

typedef __bf16 bf16x8 __attribute__((ext_vector_type(8)));
typedef float f32x4 __attribute__((ext_vector_type(4)));

__device__ __forceinline__ unsigned short f2bf(float a) {
    unsigned u = __builtin_bit_cast(unsigned, a);
    return (unsigned short)((u + 0x7fffu + ((u >> 16) & 1u)) >> 16);
}
__device__ __forceinline__ unsigned f2bf2(float a, float b) {
    return (unsigned)f2bf(a) | ((unsigned)f2bf(b) << 16);
}
__device__ __forceinline__ float bf2f(unsigned short u) {
    return __builtin_bit_cast(float, ((unsigned)u) << 16);
}

__device__ __forceinline__ void gload_lds16(const void* g, void* l) {
    __builtin_amdgcn_global_load_lds(
        (const __attribute__((address_space(1))) void*)g,
        (__attribute__((address_space(3))) void*)l, 16, 0, 0);
}

// ---------------- convert: x and W -> pre-swizzled bf16 (proven R2 scheme) ---
// Row stride 8192B. Logical 16B granule k16 of row r lives at byte
// (k16>>3)*128 + (((k16&7)^(r&7))*16.
__global__ __launch_bounds__(256) void k_cvt(const float* __restrict__ x,
                                             const float* __restrict__ W,
                                             unsigned char* __restrict__ xb,
                                             unsigned char* __restrict__ Wb) {
    int blk = blockIdx.x;
    if (blk < 1024) {                          // x: 512 rows x 512 granules
        int g = blk * 256 + threadIdx.x;
        int r = g >> 9, k16 = g & 511;
        const float4* p = (const float4*)(x + (size_t)r * INFEAT + k16 * 8);
        float4 v0 = p[0], v1 = p[1];
        uint4 o;
        o.x = f2bf2(v0.x, v0.y); o.y = f2bf2(v0.z, v0.w);
        o.z = f2bf2(v1.x, v1.y); o.w = f2bf2(v1.z, v1.w);
        *(uint4*)(xb + (size_t)r * 8192 + (k16 >> 3) * 128 + (((k16 & 7) ^ (r & 7)) * 16)) = o;
    } else {                                    // W: 1024 rows x 512 granules
        int g = (blk - 1024) * 256 + threadIdx.x;
        int r = g >> 9, k16 = g & 511;
        uint4 o = {0, 0, 0, 0};
        if (r < LOUT) {
            const float4* p = (const float4*)(W + (size_t)r * INFEAT + k16 * 8);
            float4 v0 = p[0], v1 = p[1];
            o.x = f2bf2(v0.x, v0.y); o.y = f2bf2(v0.z, v0.w);
            o.z = f2bf2(v1.x, v1.y); o.w = f2bf2(v1.z, v1.w);
        }
        *(uint4*)(Wb + (size_t)r * 8192 + (k16 >> 3) * 128 + (((k16 & 7) ^ (r & 7)) * 16)) = o;
    }
}

// ---------------- GEMM: partial[s] = xb @ Wb^T (zero-barrier K-loop) --------
// NEW STRUCTURE CLASS (R12 post-mortem: all barrier-per-K-step variants pin
// at ~250 TF). Block (rg,bn,sp): rows rg*64..+64, cols bn*64..+64, k-slice
// sp*512..+512. The WHOLE A-tile (64 rows x 512k bf16 = 64KB) is glds-staged
// once — the xb pre-swizzle and the LDS slot swizzle (slot = kg^(row&7))
// cancel, so the copy is LINEAR: src = row*8192 + sp*1024 + lane*16,
// dest = row*1024. One __syncthreads. Then a BARRIER-FREE K-loop: per wave,
// B-frags stream straight from Wb (global, XCD-L2-resident) into a 3-set
// register rotation loaded 2 ks ahead; 16 lds b128 : 64 B-loads : 64 MFMA.
// 4 independent MFMA chains (one per n-frag). Grid 1024 = 2 blocks/CU
// (LDS 64KB). XCD chunk: work = xcd*128 + idx -> each XCD owns one sp slice
// (xb 0.5MB + Wb 1MB working set, L2-resident).
__global__ __launch_bounds__(256, 2) void k_gemm(
    const unsigned char* __restrict__ xb, const unsigned char* __restrict__ Wb,
    unsigned short* __restrict__ partial) {
    __shared__ unsigned char lA[65536];       // 64 rows x 1024B, swizzled
    const int bid = blockIdx.x;
    const int work = (bid & 7) * 128 + (bid >> 3);
    const int sp = work >> 7, rg = (work >> 4) & 7, bn = work & 15;
    const int tid = threadIdx.x;
    const int wave = tid >> 6, lane = tid & 63;
    const int lrow = lane & 15, lgrp = lane >> 4;
    const int arow0 = rg * 64, brow0 = bn * 64;
    const int m0 = wave * 16;                 // wave's 16-row output stripe

    // ---- one-time A stage: 16 linear 1KB glds per wave ----
#pragma unroll
    for (int i = 0; i < 16; ++i) {
        int row = wave * 16 + i;
        gload_lds16(xb + (size_t)(arow0 + row) * 8192 + sp * 1024 + lane * 16,
                    lA + row * 1024);
    }
    asm volatile("s_waitcnt vmcnt(0)" ::: "memory");
    __syncthreads();                          // the ONLY block-wide sync

    // ---- barrier-free K-loop ----
    f32x4 acc[4] = {};                        // one chain per n-frag
    const int lx = lrow & 7;
    size_t bbase[4];
#pragma unroll
    for (int nf = 0; nf < 4; ++nf)
        bbase[nf] = (size_t)(brow0 + nf * 16 + lrow) * 8192 + sp * 1024;

    bf16x8 bs0[4], bs1[4], bs2[4];

#define LOADB(KS, SET)                                                        \
    {                                                                         \
        _Pragma("unroll")                                                     \
        for (int nf = 0; nf < 4; ++nf)                                        \
            SET[nf] = *(const bf16x8*)(Wb + bbase[nf] +                       \
                                       ((((KS) * 4 + lgrp) ^ lx) * 16));      \
    }
#define KS3(KS, CUR, NXT)                                                     \
    {                                                                         \
        if ((KS) + 2 < 16) LOADB((KS) + 2, NXT);                              \
        bf16x8 af = *(const bf16x8*)(lA + (m0 + lrow) * 1024 +                \
                                     ((((KS) * 4 + lgrp) ^ lx) * 16));        \
        _Pragma("unroll")                                                     \
        for (int nf = 0; nf < 4; ++nf)                                        \
            acc[nf] = __builtin_amdgcn_mfma_f32_16x16x32_bf16(                \
                af, CUR[nf], acc[nf], 0, 0, 0);                               \
    }

    LOADB(0, bs0)
    LOADB(1, bs1)
    KS3(0, bs0, bs2)  KS3(1, bs1, bs0)  KS3(2, bs2, bs1)
    KS3(3, bs0, bs2)  KS3(4, bs1, bs0)  KS3(5, bs2, bs1)
    KS3(6, bs0, bs2)  KS3(7, bs1, bs0)  KS3(8, bs2, bs1)
    KS3(9, bs0, bs2)  KS3(10, bs1, bs0) KS3(11, bs2, bs1)
    KS3(12, bs0, bs2) KS3(13, bs1, bs0) KS3(14, bs2, bs1)
    KS3(15, bs0, bs2)
#undef KS3
#undef LOADB

    // ---- epilogue: bf16 partials ----
    unsigned short* P = partial + (size_t)sp * (BATCH * NPAD);
#pragma unroll
    for (int nf = 0; nf < 4; ++nf)
#pragma unroll
        for (int reg = 0; reg < 4; ++reg) {
            int r = arow0 + m0 + lgrp * 4 + reg;
            int c = brow0 + nf * 16 + lrow;
            P[(size_t)r * NPAD + c] = f2bf(acc[nf][reg]);
        }
}

// ---------------- fused: split-K reduce + bias + tanh + FWHT + inv + norm ----
// One block per batch row. dot[c] = sum_j h[j]*H[c][j+1] = FWHT(g)[c] with
// g[0]=0, g[k]=h[k-1]  (Sylvester H symmetric; H[c][0]*g[0]=0 drops out).
__global__ __launch_bounds__(256) void k_fused(const unsigned short* __restrict__ partial,
                                               const float* __restrict__ bias,
                                               const float* __restrict__ epsp,
                                               const float* __restrict__ powp,
                                               float* __restrict__ out) {
    __shared__ float g[1024];
    __shared__ float wsum[4];
    const int r = blockIdx.x, t = threadIdx.x;
    const int n0 = t * 4;

    f32x4 v = {0.0f, 0.0f, 0.0f, 0.0f};
#pragma unroll
    for (int s = 0; s < SPLITK; ++s) {
        ushort4 p = *(const ushort4*)(partial + ((size_t)s * BATCH + r) * NPAD + n0);
        v[0] += bf2f(p.x); v[1] += bf2f(p.y); v[2] += bf2f(p.z); v[3] += bf2f(p.w);
    }
    float bb[4];
    if (t < 255) {
        float4 b4 = *(const float4*)(bias + n0);
        bb[0] = b4.x; bb[1] = b4.y; bb[2] = b4.z; bb[3] = b4.w;
    } else {
        bb[0] = bias[1020]; bb[1] = bias[1021]; bb[2] = bias[1022]; bb[3] = 0.0f;
    }
    if (t == 0) g[0] = 0.0f;
#pragma unroll
    for (int j = 0; j < 4; ++j) {
        int n = n0 + j;
        if (n < LOUT) g[n + 1] = tanhf(v[j] + bb[j]);
    }
    __syncthreads();

    // FWHT: 10 stages, 512 butterflies/stage, 2 per thread
#pragma unroll 1
    for (int s = 0; s < 10; ++s) {
        int st = 1 << s;
#pragma unroll
        for (int pp = 0; pp < 2; ++pp) {
            int p = t + pp * 256;
            int idx = ((p >> s) << (s + 1)) | (p & (st - 1));
            float a = g[idx], c = g[idx + st];
            g[idx] = a + c;
            g[idx + st] = a - c;
        }
        __syncthreads();
    }

    const float eps = *epsp, pw = *powp;
    float iv[4];
    float ss = 0.0f;
#pragma unroll
    for (int j = 0; j < 4; ++j) {
        int c = n0 + j;
        float d = fmaxf(1023.0f - g[c], eps);
        float q = (pw == 1.0f) ? (1.0f / d) : powf(d, -pw);
        if (c >= NCLS) q = 0.0f;
        iv[j] = q;
        ss += q;
    }
#pragma unroll
    for (int m = 32; m; m >>= 1) ss += __shfl_xor(ss, m, 64);
    if ((t & 63) == 0) wsum[t >> 6] = ss;
    __syncthreads();
    float sc = 1.0f / (wsum[0] + wsum[1] + wsum[2] + wsum[3]);

    if (n0 < NCLS) {  // NCLS = 1000 = 4*250: threads 0..249 store full float4
        float4 o;
        o.x = iv[0] * sc; o.y = iv[1] * sc; o.z = iv[2] * sc; o.w = iv[3] * sc;
        *(float4*)(out + (size_t)r * NCLS + n0) = o;
    }
}

extern "C" void kernel_launch(void* const* d_in, const int* in_sizes, int n_in,
                              void* d_out, int out_size, void* d_ws, size_t ws_size,
                              hipStream_t stream) {
    const float* x = (const float*)d_in[0];       // (512, 4096)
    const float* W = (const float*)d_in[1];       // (1023, 4096)
    const float* b = (const float*)d_in[2];       // (1023,)
    // d_in[3] = labels: NOT needed (Hadamard structure -> FWHT)
    const float* epsp = (const float*)d_in[4];
    const float* powp = (const float*)d_in[5];
    float* out = (float*)d_out;                   // (512, 1000)

    unsigned char* ws = (unsigned char*)d_ws;
    unsigned char* xb = ws;                          // 4 MB (512 x 4096 bf16, swz)
    unsigned char* Wb = ws + (4u << 20);             // 8 MB (1024 x 4096 bf16, swz)
    unsigned short* partial = (unsigned short*)(ws + (12u << 20));  // 8 MB

    k_cvt<<<3072, 256, 0, stream>>>(x, W, xb, Wb);
    k_gemm<<<1024, 256, 0, stream>>>(xb, Wb, partial);
    k_fused<<<512, 256, 0, stream>>>(partial, b, epsp, powp, out);
}

// Round 14
// 28.297 us; speedup vs baseline: 1.3804x; 1.3804x over previous
//
#include <hip/hip_runtime.h>

// Problem constants
#define BATCH 512
#define INFEAT 4096
#define LOUT 1023   // code_length - 1
#define NCLS 1000
#define NPAD 1024
#define SPLITK 16

typedef __bf16 bf16x8 __attribute__((ext_vector_type(8)));
typedef float f32x4 __attribute__((ext_vector_type(4)));

__device__ __forceinline__ unsigned short f2bf(float a) {
    unsigned u = __builtin_bit_cast(unsigned, a);
    return (unsigned short)((u + 0x7fffu + ((u >> 16) & 1u)) >> 16);
}
__device__ __forceinline__ unsigned f2bf2(float a, float b) {
    return (unsigned)f2bf(a) | ((unsigned)f2bf(b) << 16);
}
__device__ __forceinline__ float bf2f(unsigned short u) {
    return __builtin_bit_cast(float, ((unsigned)u) << 16);
}

__device__ __forceinline__ void gload_lds16(const void* g, void* l) {
    __builtin_amdgcn_global_load_lds(
        (const __attribute__((address_space(1))) void*)g,
        (__attribute__((address_space(3))) void*)l, 16, 0, 0);
}

// ---------------- convert: x and W -> pre-swizzled bf16 (proven R2 scheme) ---
// Row stride 8192B. Logical 16B granule k16 of row r lives at byte
// (k16>>3)*128 + ((k16&7)^(r&7))*16. BW-floor kernel (~37 MB -> ~6 us).
__global__ __launch_bounds__(256) void k_cvt(const float* __restrict__ x,
                                             const float* __restrict__ W,
                                             unsigned char* __restrict__ xb,
                                             unsigned char* __restrict__ Wb) {
    int blk = blockIdx.x;
    if (blk < 1024) {                          // x: 512 rows x 512 granules
        int g = blk * 256 + threadIdx.x;
        int r = g >> 9, k16 = g & 511;
        const float4* p = (const float4*)(x + (size_t)r * INFEAT + k16 * 8);
        float4 v0 = p[0], v1 = p[1];
        uint4 o;
        o.x = f2bf2(v0.x, v0.y); o.y = f2bf2(v0.z, v0.w);
        o.z = f2bf2(v1.x, v1.y); o.w = f2bf2(v1.z, v1.w);
        *(uint4*)(xb + (size_t)r * 8192 + (k16 >> 3) * 128 + (((k16 & 7) ^ (r & 7)) * 16)) = o;
    } else {                                    // W: 1024 rows x 512 granules
        int g = (blk - 1024) * 256 + threadIdx.x;
        int r = g >> 9, k16 = g & 511;
        uint4 o = {0, 0, 0, 0};
        if (r < LOUT) {
            const float4* p = (const float4*)(W + (size_t)r * INFEAT + k16 * 8);
            float4 v0 = p[0], v1 = p[1];
            o.x = f2bf2(v0.x, v0.y); o.y = f2bf2(v0.z, v0.w);
            o.z = f2bf2(v1.x, v1.y); o.w = f2bf2(v1.z, v1.w);
        }
        *(uint4*)(Wb + (size_t)r * 8192 + (k16 >> 3) * 128 + (((k16 & 7) ^ (r & 7)) * 16)) = o;
    }
}

// ---------------- GEMM: partial[s] = xb @ Wb^T (m97 geometry + split-K) -----
// R13 post-mortem model: per-CU ds_read_b128 issue (12 cyc ea) dominated all
// prior configs (MFMA:read ratio <=1.33). This config = m97's proven shape:
// BM=BN=128, BK=64, 4 waves (2x2), wave-tile 64x64 (acc[4][4]) -> per K-step
// per wave 16 ds_read : 32 MFMA (ratio 2.0), halving per-CU LDS-read time to
// ~2.6us vs MFMA 2.1us. SK=16 -> grid 512 = 2 blocks/CU co-resident (LDS
// 64KB) so the sibling block hides the per-step vmcnt(0) drain (m114).
// glds staging from pre-swizzled xb/Wb: linear dest, 8 glds/thread/step.
// Chunked XCD swizzle: 64 consecutive works = 2 sp-slices per XCD (~1.5 MB
// working set, L2-resident).
__global__ __launch_bounds__(256, 2) void k_gemm(
    const unsigned char* __restrict__ xb, const unsigned char* __restrict__ Wb,
    unsigned short* __restrict__ partial) {
    __shared__ unsigned char lds[65536];      // 2 x (16KB A + 16KB B)
    const int bid = blockIdx.x;
    const int work = (bid & 7) * 64 + (bid >> 3);   // chunked XCD swizzle
    const int bn = work & 7, bm = (work >> 3) & 3, sp = work >> 5;
    const int tid = threadIdx.x;
    const int wave = tid >> 6, lane = tid & 63;
    const int lrow = lane & 15, lgrp = lane >> 4;
    const int wr = wave >> 1, wc = wave & 1;        // 2 x 2 wave grid
    const int arow0 = bm * 128, brow0 = bn * 128, chunk0 = sp * 4;

    f32x4 acc[4][4] = {};

    // staging: 1024 granules per tile = 4 wave-segments of 64; linear dest.
    auto STAGE = [&](int bsel, int c) {
        unsigned char* lA = lds + bsel * 32768;
        unsigned char* lB = lA + 16384;
#pragma unroll
        for (int j = 0; j < 4; ++j) {
            int g = wave * 256 + j * 64 + lane;     // granule id 0..1023
            int r = g >> 3, s = g & 7;
            gload_lds16(xb + (size_t)(arow0 + r) * 8192 + c * 128 + s * 16,
                        lA + (wave * 256 + j * 64) * 16);
            gload_lds16(Wb + (size_t)(brow0 + r) * 8192 + c * 128 + s * 16,
                        lB + (wave * 256 + j * 64) * 16);
        }
    };

    auto COMPUTE = [&](int bsel) {
        const unsigned char* lA = lds + bsel * 32768;
        const unsigned char* lB = lA + 16384;
#pragma unroll
        for (int ks = 0; ks < 2; ++ks) {
            int swz = ((ks * 4 + lgrp) ^ (lrow & 7)) * 16;
            bf16x8 fa[4], fb[4];
#pragma unroll
            for (int m = 0; m < 4; ++m)
                fa[m] = *(const bf16x8*)(lA + (wr * 64 + m * 16 + lrow) * 128 + swz);
#pragma unroll
            for (int n = 0; n < 4; ++n)
                fb[n] = *(const bf16x8*)(lB + (wc * 64 + n * 16 + lrow) * 128 + swz);
            __builtin_amdgcn_s_setprio(1);
#pragma unroll
            for (int m = 0; m < 4; ++m)
#pragma unroll
                for (int n = 0; n < 4; ++n)
                    acc[m][n] = __builtin_amdgcn_mfma_f32_16x16x32_bf16(
                        fa[m], fb[n], acc[m][n], 0, 0, 0);
            __builtin_amdgcn_s_setprio(0);
        }
    };

    // --- lean 2-phase loop: 4 K-steps (K=256 per block) ---
    STAGE(0, chunk0);
    asm volatile("s_waitcnt vmcnt(0)" ::: "memory");
    __builtin_amdgcn_s_barrier();
#pragma unroll 1
    for (int t = 0; t < 4; ++t) {
        const int cur = t & 1;
        if (t + 1 < 4) STAGE(cur ^ 1, chunk0 + t + 1);
        COMPUTE(cur);
        asm volatile("s_waitcnt vmcnt(0) lgkmcnt(0)" ::: "memory");
        __builtin_amdgcn_s_barrier();
    }

    // --- epilogue: bf16 partials ---
    unsigned short* P = partial + (size_t)sp * (BATCH * NPAD);
#pragma unroll
    for (int m = 0; m < 4; ++m)
#pragma unroll
        for (int n = 0; n < 4; ++n)
#pragma unroll
            for (int reg = 0; reg < 4; ++reg) {
                int r = arow0 + wr * 64 + m * 16 + lgrp * 4 + reg;
                int c = brow0 + wc * 64 + n * 16 + lrow;
                P[(size_t)r * NPAD + c] = f2bf(acc[m][n][reg]);
            }
}

// ---------------- fused: split-K reduce + bias + tanh + FWHT + inv + norm ----
// One block per batch row. dot[c] = sum_j h[j]*H[c][j+1] = FWHT(g)[c] with
// g[0]=0, g[k]=h[k-1]  (Sylvester H symmetric; H[c][0]*g[0]=0 drops out).
__global__ __launch_bounds__(256) void k_fused(const unsigned short* __restrict__ partial,
                                               const float* __restrict__ bias,
                                               const float* __restrict__ epsp,
                                               const float* __restrict__ powp,
                                               float* __restrict__ out) {
    __shared__ float g[1024];
    __shared__ float wsum[4];
    const int r = blockIdx.x, t = threadIdx.x;
    const int n0 = t * 4;

    f32x4 v = {0.0f, 0.0f, 0.0f, 0.0f};
#pragma unroll
    for (int s = 0; s < SPLITK; ++s) {
        ushort4 p = *(const ushort4*)(partial + ((size_t)s * BATCH + r) * NPAD + n0);
        v[0] += bf2f(p.x); v[1] += bf2f(p.y); v[2] += bf2f(p.z); v[3] += bf2f(p.w);
    }
    float bb[4];
    if (t < 255) {
        float4 b4 = *(const float4*)(bias + n0);
        bb[0] = b4.x; bb[1] = b4.y; bb[2] = b4.z; bb[3] = b4.w;
    } else {
        bb[0] = bias[1020]; bb[1] = bias[1021]; bb[2] = bias[1022]; bb[3] = 0.0f;
    }
    if (t == 0) g[0] = 0.0f;
#pragma unroll
    for (int j = 0; j < 4; ++j) {
        int n = n0 + j;
        if (n < LOUT) g[n + 1] = tanhf(v[j] + bb[j]);
    }
    __syncthreads();

    // FWHT: 10 stages, 512 butterflies/stage, 2 per thread
#pragma unroll 1
    for (int s = 0; s < 10; ++s) {
        int st = 1 << s;
#pragma unroll
        for (int pp = 0; pp < 2; ++pp) {
            int p = t + pp * 256;
            int idx = ((p >> s) << (s + 1)) | (p & (st - 1));
            float a = g[idx], c = g[idx + st];
            g[idx] = a + c;
            g[idx + st] = a - c;
        }
        __syncthreads();
    }

    const float eps = *epsp, pw = *powp;
    float iv[4];
    float ss = 0.0f;
#pragma unroll
    for (int j = 0; j < 4; ++j) {
        int c = n0 + j;
        float d = fmaxf(1023.0f - g[c], eps);
        float q = (pw == 1.0f) ? (1.0f / d) : powf(d, -pw);
        if (c >= NCLS) q = 0.0f;
        iv[j] = q;
        ss += q;
    }
#pragma unroll
    for (int m = 32; m; m >>= 1) ss += __shfl_xor(ss, m, 64);
    if ((t & 63) == 0) wsum[t >> 6] = ss;
    __syncthreads();
    float sc = 1.0f / (wsum[0] + wsum[1] + wsum[2] + wsum[3]);

    if (n0 < NCLS) {  // NCLS = 1000 = 4*250: threads 0..249 store full float4
        float4 o;
        o.x = iv[0] * sc; o.y = iv[1] * sc; o.z = iv[2] * sc; o.w = iv[3] * sc;
        *(float4*)(out + (size_t)r * NCLS + n0) = o;
    }
}

extern "C" void kernel_launch(void* const* d_in, const int* in_sizes, int n_in,
                              void* d_out, int out_size, void* d_ws, size_t ws_size,
                              hipStream_t stream) {
    const float* x = (const float*)d_in[0];       // (512, 4096)
    const float* W = (const float*)d_in[1];       // (1023, 4096)
    const float* b = (const float*)d_in[2];       // (1023,)
    // d_in[3] = labels: NOT needed (Hadamard structure -> FWHT)
    const float* epsp = (const float*)d_in[4];
    const float* powp = (const float*)d_in[5];
    float* out = (float*)d_out;                   // (512, 1000)

    unsigned char* ws = (unsigned char*)d_ws;
    unsigned char* xb = ws;                          // 4 MB (512 x 4096 bf16, swz)
    unsigned char* Wb = ws + (4u << 20);             // 8 MB (1024 x 4096 bf16, swz)
    unsigned short* partial = (unsigned short*)(ws + (12u << 20));  // 16 MB

    k_cvt<<<3072, 256, 0, stream>>>(x, W, xb, Wb);
    k_gemm<<<512, 256, 0, stream>>>(xb, Wb, partial);
    k_fused<<<512, 256, 0, stream>>>(partial, b, epsp, powp, out);
}